// Round 5
// baseline (6048.464 us; speedup 1.0000x reference)
//
#include <hip/hip_runtime.h>

#define B64 64
#define SE 512
#define HD 1024
#define ED 512
#define NV 10000
#define TT 20
#define MM 1536
#define MASK_VALF -10000000.0f

// ---- workspace offsets (floats) ----
#define OFF_XT    0                    // inpT [512][64]
#define OFF_HA    32768                // hA [1024][64]
#define OFF_HB    98304                // hB [1024][64]
#define OFF_CT    163840               // cT [1024][64]
#define OFF_A     229376               // REGION A: H1P[12][1536][64] | LP[6][10000][64] (3.84M)
#define OFF_B     4069376              // REGION B: QPART[8][1024][64] | FACC[512][1024] (524288)
#define OFF_QF    4593664              // qf [64][1024]
#define OFF_FM    4659200              // [512]
#define OFF_FL    4659712              // [512]
#define OFF_XT2   4660224              // [1536][64]
#define OFF_H1T   4758528              // [1536][64]
#define OFF_ARGV  4856832              // [1250][64]
#define OFF_ARGI  4936832              // [1250][64] (int)
#define OFF_MASKT 5016832              // [10000][64]
#define OFF_BUF   5656832              // [64][20][512]
#define OFF_BUFT  6312192              // [512][20][64]
#define OFF_KVP   6967552              // [64][20][64]
#define OFF_CNT   7049472              // [64] int
// end: ~7.05M floats ~= 28.2 MB

__device__ __forceinline__ float sigmoidf_(float x) { return 1.f / (1.f + expf(-x)); }

// ---------------- init ----------------
__global__ __launch_bounds__(256) void k_init(const float* __restrict__ h0,
                                              const float* __restrict__ c0,
                                              float* __restrict__ ws) {
  int idx = blockIdx.x * 256 + threadIdx.x, stride = gridDim.x * 256;
  float* inpT = ws + OFF_XT;
  float* hA = ws + OFF_HA;
  float* cT = ws + OFF_CT;
  float* maskT = ws + OFF_MASKT;
  float* buf = ws + OFF_BUF;
  float* bufT = ws + OFF_BUFT;
  int* cnt = (int*)(ws + OFF_CNT);
  for (int i = idx; i < 512 * 64; i += stride) inpT[i] = 0.f;
  for (int i = idx; i < NV * 64; i += stride) maskT[i] = 0.f;
  for (int i = idx; i < B64 * TT * ED; i += stride) { buf[i] = 0.f; bufT[i] = 0.f; }
  for (int i = idx; i < HD * 64; i += stride) {
    int u = i >> 6, b = i & 63;
    hA[i] = h0[b * HD + u];
    cT[i] = c0[b * HD + u];
  }
  if (idx < 64) cnt[idx] = 0;
}

// ---------------- fused LSTM cell: gates GEMM (2-phase LDS staging) + pointwise ----------------
// block = 2 u's x 4 gates (8 rows); wave g computes gate g for j=0,1.
__global__ __launch_bounds__(256) void k_cell(const float* __restrict__ inpT,
                                              const float* __restrict__ h_in,
                                              const float* __restrict__ w_ih,
                                              const float* __restrict__ w_hh,
                                              const float* __restrict__ b_ih,
                                              const float* __restrict__ b_hh,
                                              float* __restrict__ cT,
                                              float* __restrict__ h_out) {
  __shared__ float wl[8 * 1024];
  __shared__ float ex[8][64];
  int tid = threadIdx.x, lane = tid & 63, wid = tid >> 6;
  int u0 = blockIdx.x * 2;
  int r0 = wid * 1024 + u0;
  float acc0 = b_ih[r0] + b_hh[r0];
  float acc1 = b_ih[r0 + 1] + b_hh[r0 + 1];
  // phase 1: w_ih rows (8 x 512)
  for (int i = tid; i < 1024; i += 256) {
    int rr = i >> 7, kk = (i & 127) * 4;
    *(float4*)&wl[rr * 512 + kk] =
        *(const float4*)&w_ih[(size_t)((rr >> 1) * 1024 + u0 + (rr & 1)) * 512 + kk];
  }
  __syncthreads();
  {
    const float* xp = inpT + lane;
    const float* w0p = &wl[(wid * 2 + 0) * 512];
    const float* w1p = &wl[(wid * 2 + 1) * 512];
#pragma unroll 2
    for (int k4 = 0; k4 < 128; ++k4) {
      float x0 = xp[(4 * k4 + 0) * 64];
      float x1 = xp[(4 * k4 + 1) * 64];
      float x2 = xp[(4 * k4 + 2) * 64];
      float x3 = xp[(4 * k4 + 3) * 64];
      float4 wa = *(const float4*)&w0p[4 * k4];
      float4 wb = *(const float4*)&w1p[4 * k4];
      acc0 = fmaf(wa.x, x0, acc0); acc1 = fmaf(wb.x, x0, acc1);
      acc0 = fmaf(wa.y, x1, acc0); acc1 = fmaf(wb.y, x1, acc1);
      acc0 = fmaf(wa.z, x2, acc0); acc1 = fmaf(wb.z, x2, acc1);
      acc0 = fmaf(wa.w, x3, acc0); acc1 = fmaf(wb.w, x3, acc1);
    }
  }
  __syncthreads();
  // phase 2: w_hh rows (8 x 1024)
  for (int i = tid; i < 2048; i += 256) {
    int rr = i >> 8, kk = (i & 255) * 4;
    *(float4*)&wl[rr * 1024 + kk] =
        *(const float4*)&w_hh[(size_t)((rr >> 1) * 1024 + u0 + (rr & 1)) * 1024 + kk];
  }
  __syncthreads();
  {
    const float* xp = h_in + lane;
    const float* w0p = &wl[(wid * 2 + 0) * 1024];
    const float* w1p = &wl[(wid * 2 + 1) * 1024];
#pragma unroll 2
    for (int k4 = 0; k4 < 256; ++k4) {
      float x0 = xp[(4 * k4 + 0) * 64];
      float x1 = xp[(4 * k4 + 1) * 64];
      float x2 = xp[(4 * k4 + 2) * 64];
      float x3 = xp[(4 * k4 + 3) * 64];
      float4 wa = *(const float4*)&w0p[4 * k4];
      float4 wb = *(const float4*)&w1p[4 * k4];
      acc0 = fmaf(wa.x, x0, acc0); acc1 = fmaf(wb.x, x0, acc1);
      acc0 = fmaf(wa.y, x1, acc0); acc1 = fmaf(wb.y, x1, acc1);
      acc0 = fmaf(wa.z, x2, acc0); acc1 = fmaf(wb.z, x2, acc1);
      acc0 = fmaf(wa.w, x3, acc0); acc1 = fmaf(wb.w, x3, acc1);
    }
  }
  ex[wid * 2 + 0][lane] = acc0;
  ex[wid * 2 + 1][lane] = acc1;
  __syncthreads();
  if (tid < 128) {
    int j = tid >> 6, b = tid & 63;
    int u = u0 + j;
    float gi = ex[0 + j][b];
    float gf = ex[2 + j][b];
    float gg = ex[4 + j][b];
    float go = ex[6 + j][b];
    float c = cT[u * 64 + b];
    float cn = sigmoidf_(gf) * c + sigmoidf_(gi) * tanhf(gg);
    float hn = sigmoidf_(go) * tanhf(cn);
    cT[u * 64 + b] = cn;
    h_out[u * 64 + b] = hn;
  }
}

// ================= generic LDS-staged thin GEMM =================
template <int KT>
__global__ __launch_bounds__(256) void k_gemm(const float* __restrict__ W, int ldW,
                                              const float* __restrict__ x,
                                              float* __restrict__ part, int nrows, size_t psz) {
  __shared__ float wl[32][KT];
  int tid = threadIdx.x;
  int r0b = blockIdx.x * 32;
  int split = blockIdx.y;
  int k0 = split * KT;
  constexpr int NF4 = 32 * KT / 4;
  for (int i = tid; i < NF4; i += 256) {
    int r = i / (KT / 4), kk = (i % (KT / 4)) * 4;
    int gr = r0b + r;
    if (gr > nrows - 1) gr = nrows - 1;
    *(float4*)&wl[r][kk] = *(const float4*)&W[(size_t)gr * ldW + k0 + kk];
  }
  __syncthreads();
  int lane = tid & 63, wid = tid >> 6;
  const float* xp = x + (size_t)k0 * 64 + lane;
  float acc[8] = {0, 0, 0, 0, 0, 0, 0, 0};
#pragma unroll 2
  for (int k4 = 0; k4 < KT / 4; ++k4) {
    float x0 = xp[(4 * k4 + 0) * 64];
    float x1 = xp[(4 * k4 + 1) * 64];
    float x2 = xp[(4 * k4 + 2) * 64];
    float x3 = xp[(4 * k4 + 3) * 64];
#pragma unroll
    for (int i = 0; i < 8; ++i) {
      const float4 w4 = *(const float4*)&wl[wid * 8 + i][4 * k4];
      acc[i] = fmaf(w4.x, x0, acc[i]);
      acc[i] = fmaf(w4.y, x1, acc[i]);
      acc[i] = fmaf(w4.z, x2, acc[i]);
      acc[i] = fmaf(w4.w, x3, acc[i]);
    }
  }
  int r0 = r0b + wid * 8;
  float* o = part + (size_t)split * psz + (size_t)r0 * 64 + lane;
#pragma unroll
  for (int i = 0; i < 8; ++i)
    if (r0 + i < nrows) o[i * 64] = acc[i];
}

// ---------------- combine q splits + b_q -> qf[b][h] (transposed via LDS) ----------------
__global__ __launch_bounds__(256) void k_qfin(const float* __restrict__ qpart,
                                              const float* __restrict__ b_q,
                                              float* __restrict__ qf) {
  __shared__ float tile[64][65];
  int h0 = blockIdx.x * 64;
  int lane = threadIdx.x & 63, hrow = threadIdx.x >> 6;
#pragma unroll
  for (int p = 0; p < 16; ++p) {
    int hl = p * 4 + hrow;
    int h = h0 + hl;
    float v = b_q[h];
#pragma unroll
    for (int s = 0; s < 8; ++s) v += qpart[((size_t)s * 1024 + h) * 64 + lane];
    tile[hl][lane] = v;
  }
  __syncthreads();
#pragma unroll
  for (int p = 0; p < 16; ++p) {
    int b = p * 4 + hrow;
    qf[(size_t)b * 1024 + h0 + lane] = tile[lane][b];
  }
}

// ---------------- flash attention (8 splits) + last-block ctx combine ----------------
__global__ __launch_bounds__(256) void k_flashctx(const float* __restrict__ enc,
                                                  const int* __restrict__ tlen,
                                                  const float* __restrict__ qf,
                                                  const float* __restrict__ kvp,
                                                  const float* __restrict__ b_ko,
                                                  const float* __restrict__ buf,
                                                  const float* __restrict__ inpT,
                                                  float* __restrict__ fm, float* __restrict__ fl,
                                                  float* __restrict__ facc, int* __restrict__ cnt,
                                                  float* __restrict__ xT2, int tv) {
  __shared__ float lacc[4][1024];
  __shared__ float lml[4][2];
  __shared__ int lastflag;
  int b = blockIdx.x >> 3, split = blockIdx.x & 7;
  int tid = threadIdx.x, lane = tid & 63, wid = tid >> 6;
  int len = tlen[b];
  float qv[16];
#pragma unroll
  for (int j = 0; j < 4; ++j) {
    float4 tq = *(const float4*)&qf[(size_t)b * 1024 + j * 256 + lane * 4];
    qv[4 * j + 0] = tq.x; qv[4 * j + 1] = tq.y; qv[4 * j + 2] = tq.z; qv[4 * j + 3] = tq.w;
  }
  const float* base = enc + (size_t)b * SE * HD;
  int s0 = split * 64 + wid * 16;
  int nr = len - s0;
  nr = nr < 0 ? 0 : (nr > 16 ? 16 : nr);
  int npair = nr >> 1;

  float4 cA[4], cB[4], nA[4], nB[4];
  float m = -1e30f, l = 0.f, acc[16];
#pragma unroll
  for (int j = 0; j < 16; ++j) acc[j] = 0.f;

#define LOADROW(d, s)                                                 \
  {                                                                   \
    const float4* rp = (const float4*)(base + (size_t)(s)*HD) + lane; \
    d[0] = rp[0]; d[1] = rp[64]; d[2] = rp[128]; d[3] = rp[192];      \
  }

  if (npair > 0) { LOADROW(cA, s0); LOADROW(cB, s0 + 1); }
  for (int p = 0; p < npair; ++p) {
    if (p + 1 < npair) {
      LOADROW(nA, s0 + 2 * p + 2);
      LOADROW(nB, s0 + 2 * p + 3);
    } else if (nr & 1) {
      LOADROW(nA, s0 + nr - 1);
    }
    float d0 = 0.f, d1 = 0.f;
#pragma unroll
    for (int j = 0; j < 4; ++j) {
      d0 = fmaf(qv[4 * j + 0], cA[j].x, d0); d1 = fmaf(qv[4 * j + 0], cB[j].x, d1);
      d0 = fmaf(qv[4 * j + 1], cA[j].y, d0); d1 = fmaf(qv[4 * j + 1], cB[j].y, d1);
      d0 = fmaf(qv[4 * j + 2], cA[j].z, d0); d1 = fmaf(qv[4 * j + 2], cB[j].z, d1);
      d0 = fmaf(qv[4 * j + 3], cA[j].w, d0); d1 = fmaf(qv[4 * j + 3], cB[j].w, d1);
    }
#pragma unroll
    for (int off = 32; off; off >>= 1) { d0 += __shfl_xor(d0, off, 64); d1 += __shfl_xor(d1, off, 64); }
    d0 = __shfl(d0, 0, 64);
    d1 = __shfl(d1, 0, 64);
    float mn = fmaxf(m, fmaxf(d0, d1));
    float sc = expf(m - mn), p0 = expf(d0 - mn), p1 = expf(d1 - mn);
    l = l * sc + p0 + p1;
#pragma unroll
    for (int j = 0; j < 4; ++j) {
      acc[4 * j + 0] = fmaf(p1, cB[j].x, fmaf(p0, cA[j].x, acc[4 * j + 0] * sc));
      acc[4 * j + 1] = fmaf(p1, cB[j].y, fmaf(p0, cA[j].y, acc[4 * j + 1] * sc));
      acc[4 * j + 2] = fmaf(p1, cB[j].z, fmaf(p0, cA[j].z, acc[4 * j + 2] * sc));
      acc[4 * j + 3] = fmaf(p1, cB[j].w, fmaf(p0, cA[j].w, acc[4 * j + 3] * sc));
    }
    m = mn;
#pragma unroll
    for (int j = 0; j < 4; ++j) { cA[j] = nA[j]; cB[j] = nB[j]; }
  }
  if (nr & 1) {
    if (npair == 0) LOADROW(cA, s0);
    float d0 = 0.f;
#pragma unroll
    for (int j = 0; j < 4; ++j) {
      d0 = fmaf(qv[4 * j + 0], cA[j].x, d0);
      d0 = fmaf(qv[4 * j + 1], cA[j].y, d0);
      d0 = fmaf(qv[4 * j + 2], cA[j].z, d0);
      d0 = fmaf(qv[4 * j + 3], cA[j].w, d0);
    }
#pragma unroll
    for (int off = 32; off; off >>= 1) d0 += __shfl_xor(d0, off, 64);
    d0 = __shfl(d0, 0, 64);
    float mn = fmaxf(m, d0);
    float sc = expf(m - mn), p0 = expf(d0 - mn);
    l = l * sc + p0;
#pragma unroll
    for (int j = 0; j < 4; ++j) {
      acc[4 * j + 0] = fmaf(p0, cA[j].x, acc[4 * j + 0] * sc);
      acc[4 * j + 1] = fmaf(p0, cA[j].y, acc[4 * j + 1] * sc);
      acc[4 * j + 2] = fmaf(p0, cA[j].z, acc[4 * j + 2] * sc);
      acc[4 * j + 3] = fmaf(p0, cA[j].w, acc[4 * j + 3] * sc);
    }
    m = mn;
  }
#undef LOADROW
#pragma unroll
  for (int j = 0; j < 4; ++j)
    *(float4*)&lacc[wid][j * 256 + lane * 4] =
        make_float4(acc[4 * j], acc[4 * j + 1], acc[4 * j + 2], acc[4 * j + 3]);
  if (lane == 0) { lml[wid][0] = m; lml[wid][1] = l; }
  __syncthreads();
  float M4 = fmaxf(fmaxf(lml[0][0], lml[1][0]), fmaxf(lml[2][0], lml[3][0]));
  float w0 = expf(lml[0][0] - M4), w1 = expf(lml[1][0] - M4);
  float w2 = expf(lml[2][0] - M4), w3 = expf(lml[3][0] - M4);
  float L4 = w0 * lml[0][1] + w1 * lml[1][1] + w2 * lml[2][1] + w3 * lml[3][1];
  int p = b * 8 + split;
  for (int h = tid; h < 1024; h += 256)
    facc[(size_t)p * 1024 + h] =
        w0 * lacc[0][h] + w1 * lacc[1][h] + w2 * lacc[2][h] + w3 * lacc[3][h];
  if (tid == 0) { fm[p] = M4; fl[p] = L4; }
  // ---- last-arriving block for this b performs the combine (split-K pattern) ----
  __threadfence();
  if (tid == 0) {
    int old = atomicAdd(&cnt[b], 1);
    lastflag = (old == 7);
  }
  __syncthreads();
  if (!lastflag) return;
  if (tid == 0) cnt[b] = 0;  // reset for next step / replay
  __threadfence();
  // history softmax weights
  __shared__ float pw[TT];
  if (tid < tv) {
    float s = b_ko[0];
    for (int g = 0; g < 64; ++g) s += kvp[((size_t)g * TT + tid) * 64 + b];
    pw[tid] = s;
  }
  __syncthreads();
  float mx = -1e30f;
  for (int k = 0; k < tv; ++k) mx = fmaxf(mx, pw[k]);
  float den = 0.f;
  for (int k = 0; k < tv; ++k) den += expf(pw[k] - mx);
  float invd = 1.f / den;
  __syncthreads();
  if (tid < tv) pw[tid] = expf(pw[tid] - mx) * invd;
  __syncthreads();
  // flash combine
  float M = -1e30f;
#pragma unroll
  for (int k = 0; k < 8; ++k) M = fmaxf(M, fm[b * 8 + k]);
  float w[8];
  float L = 0.f;
#pragma unroll
  for (int k = 0; k < 8; ++k) {
    w[k] = expf(fm[b * 8 + k] - M);
    L += w[k] * fl[b * 8 + k];
  }
  float inv = 1.f / L;
  for (int h = tid; h < 1024; h += 256) {
    float s = 0.f;
#pragma unroll
    for (int k = 0; k < 8; ++k) s += w[k] * facc[(size_t)(b * 8 + k) * 1024 + h];
    xT2[h * 64 + b] = enc[(size_t)b * SE * HD + h] + s * inv;  // sent = enc[:,0,:]
  }
  for (int e = tid; e < 512; e += 256) {
    float a = 0.f;
    for (int k = 0; k < tv; ++k) a += pw[k] * buf[((size_t)b * TT + k) * 512 + e];
    xT2[(1024 + e) * 64 + b] = inpT[e * 64 + b] + a;
  }
}

// ---------------- incremental history score for buf column j ----------------
__global__ __launch_bounds__(256) void k_kscore(const float* __restrict__ bufT,
                                                const float* __restrict__ w_k,
                                                const float* __restrict__ b_k,
                                                const float* __restrict__ w_ko,
                                                float* __restrict__ kvp, int j) {
  __shared__ float sacc[4][8][64];
  int lane = threadIdx.x & 63, wid = threadIdx.x >> 6;
  int ug = blockIdx.x;  // 0..63
  int u0 = ug * 8;
  int k0 = wid * 128;
  const float* xp = bufT + (size_t)j * 64 + lane;
  float acc[8] = {0, 0, 0, 0, 0, 0, 0, 0};
  for (int k4 = 0; k4 < 32; ++k4) {
    int e = k0 + 4 * k4;
    float x0 = xp[(size_t)(e + 0) * (TT * 64)];
    float x1 = xp[(size_t)(e + 1) * (TT * 64)];
    float x2 = xp[(size_t)(e + 2) * (TT * 64)];
    float x3 = xp[(size_t)(e + 3) * (TT * 64)];
#pragma unroll
    for (int i = 0; i < 8; ++i) {
      const float4 w4 = *(const float4*)&w_k[(size_t)(u0 + i) * 512 + e];
      acc[i] = fmaf(w4.x, x0, acc[i]);
      acc[i] = fmaf(w4.y, x1, acc[i]);
      acc[i] = fmaf(w4.z, x2, acc[i]);
      acc[i] = fmaf(w4.w, x3, acc[i]);
    }
  }
#pragma unroll
  for (int i = 0; i < 8; ++i) sacc[wid][i][lane] = acc[i];
  __syncthreads();
  if (wid == 0) {
    float kp = 0.f;
#pragma unroll
    for (int i = 0; i < 8; ++i) {
      float tot = b_k[u0 + i] + sacc[0][i][lane] + sacc[1][i][lane] + sacc[2][i][lane] +
                  sacc[3][i][lane];
      kp += fmaxf(tot, 0.f) * w_ko[u0 + i];
    }
    kvp[((size_t)ug * TT + j) * 64 + lane] = kp;
  }
}

__global__ __launch_bounds__(256) void k_h1comb(const float* __restrict__ h1part,
                                                const float* __restrict__ b_m1,
                                                float* __restrict__ h1T) {
  int i = blockIdx.x * 256 + threadIdx.x;  // 98304
  int r = i >> 6;
  float v = b_m1[r];
#pragma unroll
  for (int s = 0; s < 12; ++s) v += h1part[(size_t)s * 98304 + i];
  h1T[i] = fmaxf(v, 0.f);
}

// ---------------- logits finish: combine + bias + mask + argmax + transposed out-write ----------------
__global__ __launch_bounds__(256) void k_logfin(const float* __restrict__ lp,
                                                const float* __restrict__ b_m2,
                                                const float* __restrict__ maskT,
                                                float* __restrict__ argv, int* __restrict__ argi,
                                                float* __restrict__ out, int t) {
  __shared__ float tile[32][65];
  int lane = threadIdx.x & 63, wid = threadIdx.x >> 6;
  int rg = blockIdx.x * 4 + wid;
  int nb = blockIdx.x * 32;
  if (rg < 1250) {
    int r0 = rg * 8;
    float best = -3.4e38f;
    int bi = 0;
#pragma unroll
    for (int i = 0; i < 8; ++i) {
      int r = r0 + i;
      size_t idx = (size_t)r * 64 + lane;
      float v = b_m2[r] + maskT[idx];
#pragma unroll
      for (int s = 0; s < 6; ++s) v += lp[(size_t)s * 640000 + idx];
      tile[wid * 8 + i][lane] = v;
      if (v > best) { best = v; bi = r; }  // strict >: first-max
    }
    argv[(size_t)rg * 64 + lane] = best;
    argi[(size_t)rg * 64 + lane] = bi;
  }
  __syncthreads();
  int b = threadIdx.x >> 2, q = threadIdx.x & 3;
  int nloc = q * 8;
  if (nb + nloc < NV) {
    float tmp[8];
#pragma unroll
    for (int c = 0; c < 8; ++c) tmp[c] = tile[nloc + c][b];
    float4* o = (float4*)&out[((size_t)b * TT + t) * NV + nb + nloc];
    o[0] = make_float4(tmp[0], tmp[1], tmp[2], tmp[3]);
    o[1] = make_float4(tmp[4], tmp[5], tmp[6], tmp[7]);
  }
}

// ---------------- final argmax (per-batch block) + feedback ----------------
__global__ __launch_bounds__(256) void k_final(const float* __restrict__ argv,
                                               const int* __restrict__ argi,
                                               const float* __restrict__ emb,
                                               float* __restrict__ maskT, float* __restrict__ inpT,
                                               float* __restrict__ buf, float* __restrict__ bufT,
                                               float* __restrict__ out_ids, int t) {
  __shared__ float sv[256];
  __shared__ int si_[256];
  __shared__ int sid;
  int b = blockIdx.x, tid = threadIdx.x;
  float best = -3.4e38f;
  int bi = 0x7fffffff;
  for (int g = tid; g < 1250; g += 256) {
    float v = argv[(size_t)g * 64 + b];
    int idx = argi[(size_t)g * 64 + b];
    if (v > best || (v == best && idx < bi)) { best = v; bi = idx; }
  }
  sv[tid] = best;
  si_[tid] = bi;
  __syncthreads();
  for (int off = 128; off; off >>= 1) {
    if (tid < off) {
      float v2 = sv[tid + off];
      int i2 = si_[tid + off];
      if (v2 > sv[tid] || (v2 == sv[tid] && i2 < si_[tid])) { sv[tid] = v2; si_[tid] = i2; }
    }
    __syncthreads();
  }
  if (tid == 0) {
    sid = si_[0];
    out_ids[b * TT + t] = (float)si_[0];
    if (si_[0] != 1) maskT[(size_t)si_[0] * 64 + b] = MASK_VALF;  // EOS(1) stays 0
  }
  __syncthreads();
  int id = sid;
  for (int e = tid; e < 512; e += 256) {
    float v = emb[(size_t)id * 512 + e];
    inpT[e * 64 + b] = v;
    buf[((size_t)b * TT + t) * 512 + e] = v;
    bufT[(size_t)e * (TT * 64) + t * 64 + b] = v;
  }
}

extern "C" void kernel_launch(void* const* d_in, const int* in_sizes, int n_in,
                              void* d_out, int out_size, void* d_ws, size_t ws_size,
                              hipStream_t stream) {
  const float* enc = (const float*)d_in[0];
  const float* h0 = (const float*)d_in[1];
  const float* c0 = (const float*)d_in[2];
  const int* tlen = (const int*)d_in[3];
  const float* emb = (const float*)d_in[5];
  const float* w_ih = (const float*)d_in[6];
  const float* w_hh = (const float*)d_in[7];
  const float* b_ih = (const float*)d_in[8];
  const float* b_hh = (const float*)d_in[9];
  const float* w_q = (const float*)d_in[10];
  const float* b_q = (const float*)d_in[11];
  const float* w_k = (const float*)d_in[12];
  const float* b_k = (const float*)d_in[13];
  const float* w_ko = (const float*)d_in[14];
  const float* b_ko = (const float*)d_in[15];
  const float* w_m1 = (const float*)d_in[16];
  const float* b_m1 = (const float*)d_in[17];
  const float* w_m2 = (const float*)d_in[18];
  const float* b_m2 = (const float*)d_in[19];

  float* ws = (float*)d_ws;
  float* out_logits = (float*)d_out;
  float* out_ids = out_logits + (size_t)B64 * TT * NV;

  float* inpT = ws + OFF_XT;
  float* hA = ws + OFF_HA;
  float* hB = ws + OFF_HB;

  k_init<<<2048, 256, 0, stream>>>(h0, c0, ws);
  k_kscore<<<64, 256, 0, stream>>>(ws + OFF_BUFT, w_k, b_k, w_ko, ws + OFF_KVP, 0);

  for (int t = 0; t < TT; ++t) {
    int tv = (t < 1) ? 1 : t;
    float* h_in = (t & 1) ? hB : hA;
    float* h_out = (t & 1) ? hA : hB;
    k_cell<<<512, 256, 0, stream>>>(inpT, h_in, w_ih, w_hh, b_ih, b_hh, ws + OFF_CT, h_out);
    k_gemm<128><<<dim3(32, 8), 256, 0, stream>>>(w_q, 1024, h_out, ws + OFF_B, 1024, 65536);
    k_qfin<<<16, 256, 0, stream>>>(ws + OFF_B, b_q, ws + OFF_QF);
    k_flashctx<<<512, 256, 0, stream>>>(enc, tlen, ws + OFF_QF, ws + OFF_KVP, b_ko, ws + OFF_BUF,
                                        inpT, ws + OFF_FM, ws + OFF_FL, ws + OFF_B,
                                        (int*)(ws + OFF_CNT), ws + OFF_XT2, tv);
    k_gemm<128><<<dim3(48, 12), 256, 0, stream>>>(w_m1, MM, ws + OFF_XT2, ws + OFF_A, MM, 98304);
    k_h1comb<<<384, 256, 0, stream>>>(ws + OFF_A, b_m1, ws + OFF_H1T);
    k_gemm<256><<<dim3(313, 6), 256, 0, stream>>>(w_m2, MM, ws + OFF_H1T, ws + OFF_A, NV, 640000);
    k_logfin<<<313, 256, 0, stream>>>(ws + OFF_A, b_m2, ws + OFF_MASKT, ws + OFF_ARGV,
                                      (int*)(ws + OFF_ARGI), out_logits, t);
    k_final<<<64, 256, 0, stream>>>(ws + OFF_ARGV, (int*)(ws + OFF_ARGI), emb, ws + OFF_MASKT,
                                    inpT, ws + OFF_BUF, ws + OFF_BUFT, out_ids, t);
    if (t < TT - 1)
      k_kscore<<<64, 256, 0, stream>>>(ws + OFF_BUFT, w_k, b_k, w_ko, ws + OFF_KVP, t);
  }
}

// Round 6
// 3679.395 us; speedup vs baseline: 1.6439x; 1.6439x over previous
//
#include <hip/hip_runtime.h>

#define B64 64
#define SE 512
#define HD 1024
#define ED 512
#define NV 10000
#define TT 20
#define MM 1536
#define MASK_VALF -10000000.0f

// ---- workspace offsets (floats); regions time-shared within a step ----
#define OFF_XT    0                    // xT [1536][64]; inpT=[0:512), hT=[512:1536)
#define OFF_CT    98304                // cT [1024][64]
#define OFF_A     163840               // REGION A: GPART[6][4096][64] | H1P[12][1536][64] | LP[6][10000][64] (3.84M)
#define OFF_B     4003840              // REGION B: QPART[8][1024][64] | FACC[2048][1024] (2,097,152)
#define OFF_QF    6100992              // qf [64][1024]
#define OFF_FM    6166528              // [2048]
#define OFF_FL    6168576              // [2048]
#define OFF_XT2   6170624              // [1536][64]
#define OFF_H1T   6268928              // [1536][64]
#define OFF_MASKT 6367232              // [10000][64]
#define OFF_BUF   7007232              // [64][20][512]
#define OFF_BUFT  7662592              // [512][20][64]
#define OFF_KVP   8317952              // [64][20][64]
#define OFF_PK    8399872              // [64] u64 packed argmax (128 floats)
// end: ~8400000 floats ~= 33.6 MB

__device__ __forceinline__ float sigmoidf_(float x) { return 1.f / (1.f + expf(-x)); }

// monotonic float encoding + inverted index: max(key) == (max value, then min index)
__device__ __forceinline__ unsigned long long packkey(float v, int r) {
  unsigned u = __float_as_uint(v);
  u = (u & 0x80000000u) ? ~u : (u | 0x80000000u);
  return ((unsigned long long)u << 32) | (unsigned)(0xFFFFFFFFu - (unsigned)r);
}

// ---------------- init ----------------
__global__ __launch_bounds__(256) void k_init(const float* __restrict__ h0,
                                              const float* __restrict__ c0,
                                              float* __restrict__ ws) {
  int idx = blockIdx.x * 256 + threadIdx.x, stride = gridDim.x * 256;
  float* inpT = ws + OFF_XT;
  float* hT = ws + OFF_XT + 512 * 64;
  float* cT = ws + OFF_CT;
  float* maskT = ws + OFF_MASKT;
  float* buf = ws + OFF_BUF;
  float* bufT = ws + OFF_BUFT;
  unsigned long long* pk = (unsigned long long*)(ws + OFF_PK);
  for (int i = idx; i < 512 * 64; i += stride) inpT[i] = 0.f;
  for (int i = idx; i < NV * 64; i += stride) maskT[i] = 0.f;
  for (int i = idx; i < B64 * TT * ED; i += stride) { buf[i] = 0.f; bufT[i] = 0.f; }
  for (int i = idx; i < HD * 64; i += stride) {
    int u = i >> 6, b = i & 63;
    hT[i] = h0[b * HD + u];
    cT[i] = c0[b * HD + u];
  }
  if (idx < 64) pk[idx] = 0ULL;
}

// ---------------- LSTM gates GEMM (LDS-staged, 6 K-splits of 256) ----------------
__global__ __launch_bounds__(256) void k_gates(const float* __restrict__ xt,
                                               const float* __restrict__ w_ih,
                                               const float* __restrict__ w_hh,
                                               float* __restrict__ gpart) {
  __shared__ float wl[32][256];
  int tid = threadIdx.x;
  int r0b = blockIdx.x * 32;
  int y = blockIdx.y;  // 0..5
  const float* W;
  int ldW, k0, xoff;
  if (y < 2) { W = w_ih; ldW = 512; k0 = y * 256; xoff = k0; }
  else { W = w_hh; ldW = 1024; k0 = (y - 2) * 256; xoff = 512 + k0; }
  for (int i = tid; i < 32 * 64; i += 256) {
    int r = i >> 6, kk = (i & 63) * 4;
    *(float4*)&wl[r][kk] = *(const float4*)&W[(size_t)(r0b + r) * ldW + k0 + kk];
  }
  __syncthreads();
  int lane = tid & 63, wid = tid >> 6;
  const float* xp = xt + (size_t)xoff * 64 + lane;
  float acc[8] = {0, 0, 0, 0, 0, 0, 0, 0};
#pragma unroll 2
  for (int k4 = 0; k4 < 64; ++k4) {
    float x0 = xp[(4 * k4 + 0) * 64];
    float x1 = xp[(4 * k4 + 1) * 64];
    float x2 = xp[(4 * k4 + 2) * 64];
    float x3 = xp[(4 * k4 + 3) * 64];
#pragma unroll
    for (int i = 0; i < 8; ++i) {
      const float4 w4 = *(const float4*)&wl[wid * 8 + i][4 * k4];
      acc[i] = fmaf(w4.x, x0, acc[i]);
      acc[i] = fmaf(w4.y, x1, acc[i]);
      acc[i] = fmaf(w4.z, x2, acc[i]);
      acc[i] = fmaf(w4.w, x3, acc[i]);
    }
  }
  int r0 = r0b + wid * 8;
  float* o = gpart + ((size_t)y * 262144 + (size_t)r0 * 64) + lane;
#pragma unroll
  for (int i = 0; i < 8; ++i) o[i * 64] = acc[i];
}

// ---------------- LSTM pointwise (combine 6 partials) ----------------
__global__ __launch_bounds__(256) void k_lstm(const float* __restrict__ gpart,
                                              const float* __restrict__ b_ih,
                                              const float* __restrict__ b_hh,
                                              float* __restrict__ cT, float* __restrict__ hT) {
  int i = blockIdx.x * 256 + threadIdx.x;  // 65536
  int u = i >> 6, b = i & 63;
  float g4[4];
#pragma unroll
  for (int gi = 0; gi < 4; ++gi) {
    int r = gi * 1024 + u;
    float v = b_ih[r] + b_hh[r];
#pragma unroll
    for (int y = 0; y < 6; ++y) v += gpart[(size_t)y * 262144 + (size_t)r * 64 + b];
    g4[gi] = v;
  }
  float c = cT[i];
  float cn = sigmoidf_(g4[1]) * c + sigmoidf_(g4[0]) * tanhf(g4[2]);
  float hn = sigmoidf_(g4[3]) * tanhf(cn);
  cT[i] = cn;
  hT[i] = hn;
}

// ================= generic LDS-staged thin GEMM =================
template <int KT>
__global__ __launch_bounds__(256) void k_gemm(const float* __restrict__ W, int ldW,
                                              const float* __restrict__ x,
                                              float* __restrict__ part, int nrows, size_t psz) {
  __shared__ float wl[32][KT];
  int tid = threadIdx.x;
  int r0b = blockIdx.x * 32;
  int split = blockIdx.y;
  int k0 = split * KT;
  constexpr int NF4 = 32 * KT / 4;
  for (int i = tid; i < NF4; i += 256) {
    int r = i / (KT / 4), kk = (i % (KT / 4)) * 4;
    int gr = r0b + r;
    if (gr > nrows - 1) gr = nrows - 1;
    *(float4*)&wl[r][kk] = *(const float4*)&W[(size_t)gr * ldW + k0 + kk];
  }
  __syncthreads();
  int lane = tid & 63, wid = tid >> 6;
  const float* xp = x + (size_t)k0 * 64 + lane;
  float acc[8] = {0, 0, 0, 0, 0, 0, 0, 0};
#pragma unroll 2
  for (int k4 = 0; k4 < KT / 4; ++k4) {
    float x0 = xp[(4 * k4 + 0) * 64];
    float x1 = xp[(4 * k4 + 1) * 64];
    float x2 = xp[(4 * k4 + 2) * 64];
    float x3 = xp[(4 * k4 + 3) * 64];
#pragma unroll
    for (int i = 0; i < 8; ++i) {
      const float4 w4 = *(const float4*)&wl[wid * 8 + i][4 * k4];
      acc[i] = fmaf(w4.x, x0, acc[i]);
      acc[i] = fmaf(w4.y, x1, acc[i]);
      acc[i] = fmaf(w4.z, x2, acc[i]);
      acc[i] = fmaf(w4.w, x3, acc[i]);
    }
  }
  int r0 = r0b + wid * 8;
  float* o = part + (size_t)split * psz + (size_t)r0 * 64 + lane;
#pragma unroll
  for (int i = 0; i < 8; ++i)
    if (r0 + i < nrows) o[i * 64] = acc[i];
}

// ---------------- combine q splits + b_q -> qf[b][h] (transposed via LDS) ----------------
__global__ __launch_bounds__(256) void k_qfin(const float* __restrict__ qpart,
                                              const float* __restrict__ b_q,
                                              float* __restrict__ qf) {
  __shared__ float tile[64][65];
  int h0 = blockIdx.x * 64;
  int lane = threadIdx.x & 63, hrow = threadIdx.x >> 6;
#pragma unroll
  for (int p = 0; p < 16; ++p) {
    int hl = p * 4 + hrow;
    int h = h0 + hl;
    float v = b_q[h];
#pragma unroll
    for (int s = 0; s < 8; ++s) v += qpart[((size_t)s * 1024 + h) * 64 + lane];
    tile[hl][lane] = v;
  }
  __syncthreads();
#pragma unroll
  for (int p = 0; p < 16; ++p) {
    int b = p * 4 + hrow;
    qf[(size_t)b * 1024 + h0 + lane] = tile[lane][b];
  }
}

// ---------------- flash attention: 32 s-splits, 4 rows/wave, pair-pipelined ----------------
__global__ __launch_bounds__(256) void k_flash(const float* __restrict__ enc,
                                               const int* __restrict__ tlen,
                                               const float* __restrict__ qf,
                                               float* __restrict__ fm, float* __restrict__ fl,
                                               float* __restrict__ facc) {
  __shared__ float lacc[4][1024];
  __shared__ float lml[4][2];
  int b = blockIdx.x >> 5, split = blockIdx.x & 31;
  int tid = threadIdx.x, lane = tid & 63, wid = tid >> 6;
  int len = tlen[b];
  float qv[16];
#pragma unroll
  for (int j = 0; j < 4; ++j) {
    float4 tq = *(const float4*)&qf[(size_t)b * 1024 + j * 256 + lane * 4];
    qv[4 * j + 0] = tq.x; qv[4 * j + 1] = tq.y; qv[4 * j + 2] = tq.z; qv[4 * j + 3] = tq.w;
  }
  const float* base = enc + (size_t)b * SE * HD;
  int s0 = split * 16 + wid * 4;
  int nr = len - s0;
  nr = nr < 0 ? 0 : (nr > 4 ? 4 : nr);
  int npair = nr >> 1;

  float4 cA[4], cB[4], nA[4], nB[4];
  float m = -1e30f, l = 0.f, acc[16];
#pragma unroll
  for (int j = 0; j < 16; ++j) acc[j] = 0.f;

#define LOADROW(d, s)                                                 \
  {                                                                   \
    const float4* rp = (const float4*)(base + (size_t)(s)*HD) + lane; \
    d[0] = rp[0]; d[1] = rp[64]; d[2] = rp[128]; d[3] = rp[192];      \
  }

  if (npair > 0) { LOADROW(cA, s0); LOADROW(cB, s0 + 1); }
  for (int p = 0; p < npair; ++p) {
    if (p + 1 < npair) {
      LOADROW(nA, s0 + 2 * p + 2);
      LOADROW(nB, s0 + 2 * p + 3);
    } else if (nr & 1) {
      LOADROW(nA, s0 + nr - 1);
    }
    float d0 = 0.f, d1 = 0.f;
#pragma unroll
    for (int j = 0; j < 4; ++j) {
      d0 = fmaf(qv[4 * j + 0], cA[j].x, d0); d1 = fmaf(qv[4 * j + 0], cB[j].x, d1);
      d0 = fmaf(qv[4 * j + 1], cA[j].y, d0); d1 = fmaf(qv[4 * j + 1], cB[j].y, d1);
      d0 = fmaf(qv[4 * j + 2], cA[j].z, d0); d1 = fmaf(qv[4 * j + 2], cB[j].z, d1);
      d0 = fmaf(qv[4 * j + 3], cA[j].w, d0); d1 = fmaf(qv[4 * j + 3], cB[j].w, d1);
    }
#pragma unroll
    for (int off = 32; off; off >>= 1) { d0 += __shfl_xor(d0, off, 64); d1 += __shfl_xor(d1, off, 64); }
    d0 = __shfl(d0, 0, 64);
    d1 = __shfl(d1, 0, 64);
    float mn = fmaxf(m, fmaxf(d0, d1));
    float sc = expf(m - mn), p0 = expf(d0 - mn), p1 = expf(d1 - mn);
    l = l * sc + p0 + p1;
#pragma unroll
    for (int j = 0; j < 4; ++j) {
      acc[4 * j + 0] = fmaf(p1, cB[j].x, fmaf(p0, cA[j].x, acc[4 * j + 0] * sc));
      acc[4 * j + 1] = fmaf(p1, cB[j].y, fmaf(p0, cA[j].y, acc[4 * j + 1] * sc));
      acc[4 * j + 2] = fmaf(p1, cB[j].z, fmaf(p0, cA[j].z, acc[4 * j + 2] * sc));
      acc[4 * j + 3] = fmaf(p1, cB[j].w, fmaf(p0, cA[j].w, acc[4 * j + 3] * sc));
    }
    m = mn;
#pragma unroll
    for (int j = 0; j < 4; ++j) { cA[j] = nA[j]; cB[j] = nB[j]; }
  }
  if (nr & 1) {
    if (npair == 0) LOADROW(cA, s0);
    float d0 = 0.f;
#pragma unroll
    for (int j = 0; j < 4; ++j) {
      d0 = fmaf(qv[4 * j + 0], cA[j].x, d0);
      d0 = fmaf(qv[4 * j + 1], cA[j].y, d0);
      d0 = fmaf(qv[4 * j + 2], cA[j].z, d0);
      d0 = fmaf(qv[4 * j + 3], cA[j].w, d0);
    }
#pragma unroll
    for (int off = 32; off; off >>= 1) d0 += __shfl_xor(d0, off, 64);
    d0 = __shfl(d0, 0, 64);
    float mn = fmaxf(m, d0);
    float sc = expf(m - mn), p0 = expf(d0 - mn);
    l = l * sc + p0;
#pragma unroll
    for (int j = 0; j < 4; ++j) {
      acc[4 * j + 0] = fmaf(p0, cA[j].x, acc[4 * j + 0] * sc);
      acc[4 * j + 1] = fmaf(p0, cA[j].y, acc[4 * j + 1] * sc);
      acc[4 * j + 2] = fmaf(p0, cA[j].z, acc[4 * j + 2] * sc);
      acc[4 * j + 3] = fmaf(p0, cA[j].w, acc[4 * j + 3] * sc);
    }
    m = mn;
  }
#undef LOADROW
#pragma unroll
  for (int j = 0; j < 4; ++j)
    *(float4*)&lacc[wid][j * 256 + lane * 4] =
        make_float4(acc[4 * j], acc[4 * j + 1], acc[4 * j + 2], acc[4 * j + 3]);
  if (lane == 0) { lml[wid][0] = m; lml[wid][1] = l; }
  __syncthreads();
  float M = fmaxf(fmaxf(lml[0][0], lml[1][0]), fmaxf(lml[2][0], lml[3][0]));
  float w0 = expf(lml[0][0] - M), w1 = expf(lml[1][0] - M);
  float w2 = expf(lml[2][0] - M), w3 = expf(lml[3][0] - M);
  float L = w0 * lml[0][1] + w1 * lml[1][1] + w2 * lml[2][1] + w3 * lml[3][1];
  int p = b * 32 + split;
  for (int h = tid; h < 1024; h += 256)
    facc[(size_t)p * 1024 + h] =
        w0 * lacc[0][h] + w1 * lacc[1][h] + w2 * lacc[2][h] + w3 * lacc[3][h];
  if (tid == 0) { fm[p] = M; fl[p] = L; }
}

// ---------------- fused: flash combine (32 partials) + history softmax -> xT2 ----------------
__global__ __launch_bounds__(256) void k_ctx(const float* __restrict__ enc,
                                             const float* __restrict__ fm,
                                             const float* __restrict__ fl,
                                             const float* __restrict__ facc,
                                             const float* __restrict__ kvp,
                                             const float* __restrict__ b_ko,
                                             const float* __restrict__ buf,
                                             const float* __restrict__ inpT,
                                             float* __restrict__ xT2, int tv) {
  __shared__ float pw[TT];
  int b = blockIdx.x, tid = threadIdx.x;
  if (tid < tv) {
    float s = b_ko[0];
    for (int g = 0; g < 64; ++g) s += kvp[((size_t)g * TT + tid) * 64 + b];
    pw[tid] = s;
  }
  __syncthreads();
  float mx = -1e30f;
  for (int k = 0; k < tv; ++k) mx = fmaxf(mx, pw[k]);
  float den = 0.f;
  for (int k = 0; k < tv; ++k) den += expf(pw[k] - mx);
  float invd = 1.f / den;
  __syncthreads();
  if (tid < tv) pw[tid] = expf(pw[tid] - mx) * invd;
  __syncthreads();
  float M = -1e30f;
#pragma unroll
  for (int k = 0; k < 32; ++k) M = fmaxf(M, fm[b * 32 + k]);
  float w[32];
  float L = 0.f;
#pragma unroll
  for (int k = 0; k < 32; ++k) {
    w[k] = expf(fm[b * 32 + k] - M);
    L += w[k] * fl[b * 32 + k];
  }
  float inv = 1.f / L;
  for (int h = tid; h < 1024; h += 256) {
    float s = 0.f;
#pragma unroll
    for (int k = 0; k < 32; ++k) s += w[k] * facc[(size_t)(b * 32 + k) * 1024 + h];
    xT2[h * 64 + b] = enc[(size_t)b * SE * HD + h] + s * inv;  // sent = enc[:,0,:]
  }
  for (int e = tid; e < 512; e += 256) {
    float a = 0.f;
    for (int k = 0; k < tv; ++k) a += pw[k] * buf[((size_t)b * TT + k) * 512 + e];
    xT2[(1024 + e) * 64 + b] = inpT[e * 64 + b] + a;
  }
}

// ---------------- incremental history score for buf column j ----------------
__global__ __launch_bounds__(256) void k_kscore(const float* __restrict__ bufT,
                                                const float* __restrict__ w_k,
                                                const float* __restrict__ b_k,
                                                const float* __restrict__ w_ko,
                                                float* __restrict__ kvp, int j) {
  __shared__ float sacc[4][8][64];
  int lane = threadIdx.x & 63, wid = threadIdx.x >> 6;
  int ug = blockIdx.x;  // 0..63
  int u0 = ug * 8;
  int k0 = wid * 128;
  const float* xp = bufT + (size_t)j * 64 + lane;
  float acc[8] = {0, 0, 0, 0, 0, 0, 0, 0};
  for (int k4 = 0; k4 < 32; ++k4) {
    int e = k0 + 4 * k4;
    float x0 = xp[(size_t)(e + 0) * (TT * 64)];
    float x1 = xp[(size_t)(e + 1) * (TT * 64)];
    float x2 = xp[(size_t)(e + 2) * (TT * 64)];
    float x3 = xp[(size_t)(e + 3) * (TT * 64)];
#pragma unroll
    for (int i = 0; i < 8; ++i) {
      const float4 w4 = *(const float4*)&w_k[(size_t)(u0 + i) * 512 + e];
      acc[i] = fmaf(w4.x, x0, acc[i]);
      acc[i] = fmaf(w4.y, x1, acc[i]);
      acc[i] = fmaf(w4.z, x2, acc[i]);
      acc[i] = fmaf(w4.w, x3, acc[i]);
    }
  }
#pragma unroll
  for (int i = 0; i < 8; ++i) sacc[wid][i][lane] = acc[i];
  __syncthreads();
  if (wid == 0) {
    float kp = 0.f;
#pragma unroll
    for (int i = 0; i < 8; ++i) {
      float tot = b_k[u0 + i] + sacc[0][i][lane] + sacc[1][i][lane] + sacc[2][i][lane] +
                  sacc[3][i][lane];
      kp += fmaxf(tot, 0.f) * w_ko[u0 + i];
    }
    kvp[((size_t)ug * TT + j) * 64 + lane] = kp;
  }
}

__global__ __launch_bounds__(256) void k_h1comb(const float* __restrict__ h1part,
                                                const float* __restrict__ b_m1,
                                                float* __restrict__ h1T) {
  int i = blockIdx.x * 256 + threadIdx.x;  // 98304
  int r = i >> 6;
  float v = b_m1[r];
#pragma unroll
  for (int s = 0; s < 12; ++s) v += h1part[(size_t)s * 98304 + i];
  h1T[i] = fmaxf(v, 0.f);
}

// ---------------- logits finish: combine + bias + mask + atomic argmax + transposed out ----------------
__global__ __launch_bounds__(256) void k_logfin(const float* __restrict__ lp,
                                                const float* __restrict__ b_m2,
                                                const float* __restrict__ maskT,
                                                unsigned long long* __restrict__ pk,
                                                float* __restrict__ out, int t) {
  __shared__ float tile[32][65];
  int lane = threadIdx.x & 63, wid = threadIdx.x >> 6;
  int rg = blockIdx.x * 4 + wid;
  int nb = blockIdx.x * 32;
  if (rg < 1250) {
    int r0 = rg * 8;
    float best = -3.4e38f;
    int bi = 0;
#pragma unroll
    for (int i = 0; i < 8; ++i) {
      int r = r0 + i;
      size_t idx = (size_t)r * 64 + lane;
      float v = b_m2[r] + maskT[idx];
#pragma unroll
      for (int s = 0; s < 6; ++s) v += lp[(size_t)s * 640000 + idx];
      tile[wid * 8 + i][lane] = v;
      if (v > best) { best = v; bi = r; }  // strict >: first-max
    }
    atomicMax(&pk[lane], packkey(best, bi));  // deterministic: max is order-independent
  }
  __syncthreads();
  int b = threadIdx.x >> 2, q = threadIdx.x & 3;
  int nloc = q * 8;
  if (nb + nloc < NV) {
    float tmp[8];
#pragma unroll
    for (int c = 0; c < 8; ++c) tmp[c] = tile[nloc + c][b];
    float4* o = (float4*)&out[((size_t)b * TT + t) * NV + nb + nloc];
    o[0] = make_float4(tmp[0], tmp[1], tmp[2], tmp[3]);
    o[1] = make_float4(tmp[4], tmp[5], tmp[6], tmp[7]);
  }
}

// ---------------- final: read packed argmax + feedback ----------------
__global__ __launch_bounds__(256) void k_final(unsigned long long* __restrict__ pk,
                                               const float* __restrict__ emb,
                                               float* __restrict__ maskT, float* __restrict__ inpT,
                                               float* __restrict__ buf, float* __restrict__ bufT,
                                               float* __restrict__ out_ids, int t) {
  __shared__ int sid;
  int b = blockIdx.x, tid = threadIdx.x;
  if (tid == 0) {
    unsigned long long k = pk[b];
    int r = (int)(0xFFFFFFFFu - (unsigned)(k & 0xFFFFFFFFull));
    sid = r;
    out_ids[b * TT + t] = (float)r;
    if (r != 1) maskT[(size_t)r * 64 + b] = MASK_VALF;  // EOS(1) stays 0
    pk[b] = 0ULL;                                       // reset for next step / replay
  }
  __syncthreads();
  int id = sid;
  for (int e = tid; e < 512; e += 256) {
    float v = emb[(size_t)id * 512 + e];
    inpT[e * 64 + b] = v;
    buf[((size_t)b * TT + t) * 512 + e] = v;
    bufT[(size_t)e * (TT * 64) + t * 64 + b] = v;
  }
}

extern "C" void kernel_launch(void* const* d_in, const int* in_sizes, int n_in,
                              void* d_out, int out_size, void* d_ws, size_t ws_size,
                              hipStream_t stream) {
  const float* enc = (const float*)d_in[0];
  const float* h0 = (const float*)d_in[1];
  const float* c0 = (const float*)d_in[2];
  const int* tlen = (const int*)d_in[3];
  const float* emb = (const float*)d_in[5];
  const float* w_ih = (const float*)d_in[6];
  const float* w_hh = (const float*)d_in[7];
  const float* b_ih = (const float*)d_in[8];
  const float* b_hh = (const float*)d_in[9];
  const float* w_q = (const float*)d_in[10];
  const float* b_q = (const float*)d_in[11];
  const float* w_k = (const float*)d_in[12];
  const float* b_k = (const float*)d_in[13];
  const float* w_ko = (const float*)d_in[14];
  const float* b_ko = (const float*)d_in[15];
  const float* w_m1 = (const float*)d_in[16];
  const float* b_m1 = (const float*)d_in[17];
  const float* w_m2 = (const float*)d_in[18];
  const float* b_m2 = (const float*)d_in[19];

  float* ws = (float*)d_ws;
  float* out_logits = (float*)d_out;
  float* out_ids = out_logits + (size_t)B64 * TT * NV;

  float* xt = ws + OFF_XT;  // inpT | hT
  float* hT = xt + 512 * 64;
  unsigned long long* pk = (unsigned long long*)(ws + OFF_PK);

  k_init<<<2048, 256, 0, stream>>>(h0, c0, ws);
  k_kscore<<<64, 256, 0, stream>>>(ws + OFF_BUFT, w_k, b_k, w_ko, ws + OFF_KVP, 0);

  for (int t = 0; t < TT; ++t) {
    int tv = (t < 1) ? 1 : t;
    k_gates<<<dim3(128, 6), 256, 0, stream>>>(xt, w_ih, w_hh, ws + OFF_A);
    k_lstm<<<256, 256, 0, stream>>>(ws + OFF_A, b_ih, b_hh, ws + OFF_CT, hT);
    k_gemm<128><<<dim3(32, 8), 256, 0, stream>>>(w_q, 1024, hT, ws + OFF_B, 1024, 65536);
    k_qfin<<<16, 256, 0, stream>>>(ws + OFF_B, b_q, ws + OFF_QF);
    k_flash<<<2048, 256, 0, stream>>>(enc, tlen, ws + OFF_QF, ws + OFF_FM, ws + OFF_FL,
                                      ws + OFF_B);
    k_ctx<<<64, 256, 0, stream>>>(enc, ws + OFF_FM, ws + OFF_FL, ws + OFF_B, ws + OFF_KVP, b_ko,
                                  ws + OFF_BUF, xt, ws + OFF_XT2, tv);
    k_gemm<128><<<dim3(48, 12), 256, 0, stream>>>(w_m1, MM, ws + OFF_XT2, ws + OFF_A, MM, 98304);
    k_h1comb<<<384, 256, 0, stream>>>(ws + OFF_A, b_m1, ws + OFF_H1T);
    k_gemm<256><<<dim3(313, 6), 256, 0, stream>>>(w_m2, MM, ws + OFF_H1T, ws + OFF_A, NV, 640000);
    k_logfin<<<313, 256, 0, stream>>>(ws + OFF_A, b_m2, ws + OFF_MASKT, pk, out_logits, t);
    k_final<<<64, 256, 0, stream>>>(pk, emb, ws + OFF_MASKT, xt, ws + OFF_BUF, ws + OFF_BUFT,
                                    out_ids, t);
    if (t < TT - 1)
      k_kscore<<<64, 256, 0, stream>>>(ws + OFF_BUFT, w_k, b_k, w_ko, ws + OFF_KVP, t);
  }
}